// Round 2
// baseline (2158.698 us; speedup 1.0000x reference)
//
#include <hip/hip_runtime.h>
#include <hip/hip_bf16.h>
#include <math.h>

// Problem constants (fixed by setup_inputs)
#define DIMX 48      // dim
#define HID  16      // hid
#define CCH  8       // C = hid/2
#define BB   16      // batch
#define HH   256
#define WW   256
#define HWPIX (HH * WW)            // 65536
#define NPIX  (BB * HWPIX)         // 1048576
#define LN_EPS 1e-5f
#define TILE 16
#define GRID 18                    // TILE + 2 halo

__device__ __forceinline__ float gelu_exact(float v) {
    return 0.5f * v * (1.0f + erff(v * 0.70710678118654752f));
}

// stage1 for one pixel: y = gelu(gelu(x@W1+b1)); x1 = y[:8]; n = LN(y[8:])*g+b
__device__ __forceinline__ void stage1_pixel(
    const float* __restrict__ xp,   // 48 contiguous floats
    const float* __restrict__ sW1, const float* __restrict__ sb1,
    const float* __restrict__ sg, const float* __restrict__ sbt,
    float* __restrict__ x1, float* __restrict__ n)
{
    float acc[HID];
#pragma unroll
    for (int j = 0; j < HID; ++j) acc[j] = sb1[j];
    const float4* __restrict__ xv4 = (const float4*)xp;
#pragma unroll
    for (int i = 0; i < DIMX / 4; ++i) {
        float4 v = xv4[i];
        float xs0 = v.x, xs1 = v.y, xs2 = v.z, xs3 = v.w;
        const float* w0 = &sW1[(i * 4 + 0) * HID];
        const float* w1 = &sW1[(i * 4 + 1) * HID];
        const float* w2 = &sW1[(i * 4 + 2) * HID];
        const float* w3 = &sW1[(i * 4 + 3) * HID];
#pragma unroll
        for (int j = 0; j < HID; ++j) {
            float a = acc[j];
            a = fmaf(xs0, w0[j], a);
            a = fmaf(xs1, w1[j], a);
            a = fmaf(xs2, w2[j], a);
            a = fmaf(xs3, w3[j], a);
            acc[j] = a;
        }
    }
#pragma unroll
    for (int j = 0; j < HID; ++j) acc[j] = gelu_exact(gelu_exact(acc[j]));

    // layernorm over acc[8..15]
    float m = 0.f;
#pragma unroll
    for (int c = 0; c < CCH; ++c) m += acc[CCH + c];
    m *= (1.0f / CCH);
    float var = 0.f;
#pragma unroll
    for (int c = 0; c < CCH; ++c) {
        float d = acc[CCH + c] - m;
        var = fmaf(d, d, var);
    }
    var *= (1.0f / CCH);
    const float rs = rsqrtf(var + LN_EPS);
#pragma unroll
    for (int c = 0; c < CCH; ++c) {
        x1[c] = acc[c];
        n[c] = fmaf((acc[CCH + c] - m) * rs, sg[c], sbt[c]);
    }
}

__global__ __launch_bounds__(256) void fused_kernel(
    const float* __restrict__ x,
    const float* __restrict__ W1, const float* __restrict__ b1,
    const float* __restrict__ gamma, const float* __restrict__ beta,
    const float* __restrict__ dw_w, const float* __restrict__ dw_b,
    const float* __restrict__ pw_w, const float* __restrict__ pw_b,
    const float* __restrict__ W2, const float* __restrict__ b2,
    float* __restrict__ out)
{
    __shared__ float sW1[DIMX * HID];    // 768
    __shared__ float sb1[HID];
    __shared__ float sg[CCH], sbt[CCH];
    __shared__ float sdw[CCH * 9];       // 72
    __shared__ float sdwb[CCH];
    __shared__ float spw[CCH * CCH];     // 64
    __shared__ float spwb[CCH];
    __shared__ float sW2[CCH * DIMX];    // 384
    __shared__ float sb2[DIMX];
    __shared__ float sn[GRID * GRID * CCH];  // 2592 floats = 10368 B

    const int t = threadIdx.x;
    // cooperative weight loads (disjoint thread ranges)
    for (int i = t; i < DIMX * HID; i += 256) sW1[i] = W1[i];
    for (int i = t; i < CCH * DIMX; i += 256) sW2[i] = W2[i];
    if (t < HID) sb1[t] = b1[t];
    if (t >= 16 && t < 24) { sg[t - 16] = gamma[t - 16]; sbt[t - 16] = beta[t - 16]; }
    if (t >= 32 && t < 104) sdw[t - 32] = dw_w[t - 32];
    if (t >= 104 && t < 112) sdwb[t - 104] = dw_b[t - 104];
    if (t >= 112 && t < 176) spw[t - 112] = pw_w[t - 112];
    if (t >= 176 && t < 184) spwb[t - 176] = pw_b[t - 176];
    if (t >= 184 && t < 232) sb2[t - 184] = b2[t - 184];

    const int bI = blockIdx.x >> 8;          // image
    const int tile = blockIdx.x & 255;
    const int h0 = (tile >> 4) * TILE;
    const int w0 = (tile & 15) * TILE;
    const int ty = t >> 4, tx = t & 15;
    const int h = h0 + ty, w = w0 + tx;
    const size_t pbase = (size_t)bI * HWPIX;

    __syncthreads();   // weights visible

    // --- stage1 for own pixel (x1, nc stay in registers) ---
    float x1[CCH], nc[CCH];
    stage1_pixel(x + (pbase + (size_t)h * WW + w) * DIMX, sW1, sb1, sg, sbt, x1, nc);
    {
        float4* dst = (float4*)&sn[((ty + 1) * GRID + (tx + 1)) * CCH];
        dst[0] = make_float4(nc[0], nc[1], nc[2], nc[3]);
        dst[1] = make_float4(nc[4], nc[5], nc[6], nc[7]);
    }

    // --- stage1 for halo ring (68 pixels) ---
    if (t < 68) {
        int gy, gx;
        if (t < 18)      { gy = 0;      gx = t; }
        else if (t < 36) { gy = 17;     gx = t - 18; }
        else if (t < 52) { gy = t - 35; gx = 0; }
        else             { gy = t - 51; gx = 17; }
        const int hh = h0 + gy - 1;
        const int ww = w0 + gx - 1;
        float4* rdst = (float4*)&sn[(gy * GRID + gx) * CCH];
        if (hh >= 0 && hh < HH && ww >= 0 && ww < WW) {
            float rx1[CCH], rn[CCH];
            stage1_pixel(x + (pbase + (size_t)hh * WW + ww) * DIMX, sW1, sb1, sg, sbt, rx1, rn);
            rdst[0] = make_float4(rn[0], rn[1], rn[2], rn[3]);
            rdst[1] = make_float4(rn[4], rn[5], rn[6], rn[7]);
        } else {
            rdst[0] = make_float4(0.f, 0.f, 0.f, 0.f);
            rdst[1] = make_float4(0.f, 0.f, 0.f, 0.f);
        }
    }
    __syncthreads();

    // --- stage2: depthwise 3x3 from LDS ---
    float sp[CCH];
#pragma unroll
    for (int c = 0; c < CCH; ++c) sp[c] = sdwb[c];
#pragma unroll
    for (int dh = 0; dh < 3; ++dh) {
#pragma unroll
        for (int dw = 0; dw < 3; ++dw) {
            const float4* nb = (const float4*)&sn[((ty + dh) * GRID + (tx + dw)) * CCH];
            float4 a = nb[0], b4 = nb[1];
            const float nv[CCH] = {a.x, a.y, a.z, a.w, b4.x, b4.y, b4.z, b4.w};
            const int ki = dh * 3 + dw;
#pragma unroll
            for (int c = 0; c < CCH; ++c)
                sp[c] = fmaf(nv[c], sdw[c * 9 + ki], sp[c]);
        }
    }

    // pointwise on center (nc in registers)
    float ch[CCH];
#pragma unroll
    for (int co = 0; co < CCH; ++co) {
        float a = spwb[co];
#pragma unroll
        for (int ci = 0; ci < CCH; ++ci)
            a = fmaf(nc[ci], spw[co * CCH + ci], a);
        ch[co] = a;
    }

    // gate
    float g[CCH];
#pragma unroll
    for (int c = 0; c < CCH; ++c) g[c] = x1[c] * (sp[c] * ch[c]);

    // GEMM2 + scatter to (B,48,H,W)
    float* obase = out + (size_t)bI * DIMX * HWPIX + (size_t)h * WW + w;
#pragma unroll
    for (int d = 0; d < DIMX; ++d) {
        float a = sb2[d];
#pragma unroll
        for (int c = 0; c < CCH; ++c)
            a = fmaf(g[c], sW2[c * DIMX + d], a);
        obase[(size_t)d * HWPIX] = a;
    }
}

extern "C" void kernel_launch(void* const* d_in, const int* in_sizes, int n_in,
                              void* d_out, int out_size, void* d_ws, size_t ws_size,
                              hipStream_t stream) {
    const float* x     = (const float*)d_in[0];
    const float* W1    = (const float*)d_in[1];
    const float* b1    = (const float*)d_in[2];
    const float* gamma = (const float*)d_in[3];
    const float* beta  = (const float*)d_in[4];
    const float* dw_w  = (const float*)d_in[5];
    const float* dw_b  = (const float*)d_in[6];
    const float* pw_w  = (const float*)d_in[7];
    const float* pw_b  = (const float*)d_in[8];
    const float* W2    = (const float*)d_in[9];
    const float* b2    = (const float*)d_in[10];
    float* out = (float*)d_out;

    const int blocks = BB * (HH / TILE) * (WW / TILE);   // 4096
    fused_kernel<<<blocks, 256, 0, stream>>>(x, W1, b1, gamma, beta,
                                             dw_w, dw_b, pw_w, pw_b, W2, b2, out);
}